// Round 6
// baseline (183.419 us; speedup 1.0000x reference)
//
#include <hip/hip_runtime.h>
#include <math.h>

#define B_ 2
#define T_ 1024
#define E_ 1024
#define H_ 16
#define D_ 64
#define M_ (B_*T_)

typedef __bf16 bf16x8 __attribute__((ext_vector_type(8)));
typedef __bf16 bf16x4 __attribute__((ext_vector_type(4)));
typedef float f32x4 __attribute__((ext_vector_type(4)));

// swizzled LDS addressing: row-major [rows][128 bytes], byte ^= (row&7)<<4
__device__ __forceinline__ void* ldsp(__bf16* base, int row, int byte) {
  return (char*)base + row * 128 + (byte ^ ((row & 7) << 4));
}

__device__ __forceinline__ void gload_lds16(const void* g, void* l) {
  __builtin_amdgcn_global_load_lds((const __attribute__((address_space(1))) void*)g,
                                   (__attribute__((address_space(3))) void*)l, 16, 0, 0);
}

// ---------------- K-1: f32 -> bf16 conversions (x, Wqkv, Wout) ----------------
#define XV4 524288     // (2*1024*1024)/4
#define WQV4 786432    // (3072*1024)/4
#define WOV4 262144    // (1024*1024)/4
#define TOTV4 (XV4 + WQV4 + WOV4)
__global__ __launch_bounds__(256) void conv_kernel(
    const float* __restrict__ x, const float* __restrict__ Wqkv,
    const float* __restrict__ Wout,
    __bf16* __restrict__ xb, __bf16* __restrict__ Wqkvb, __bf16* __restrict__ Woutb) {
  for (size_t i = (size_t)blockIdx.x * blockDim.x + threadIdx.x; i < TOTV4;
       i += (size_t)gridDim.x * blockDim.x) {
    const float4* src; __bf16* dst; size_t off;
    if (i < XV4)            { src = (const float4*)x;    dst = xb;    off = i; }
    else if (i < XV4+WQV4)  { src = (const float4*)Wqkv; dst = Wqkvb; off = i - XV4; }
    else                    { src = (const float4*)Wout; dst = Woutb; off = i - XV4 - WQV4; }
    float4 val = src[off];
    bf16x4 o = {(__bf16)val.x, (__bf16)val.y, (__bf16)val.z, (__bf16)val.w};
    *(bf16x4*)(dst + off * 4) = o;
  }
}

// ---------------- K0: importance (spike) + alpha (f32 — sign decision!) ----------------
__global__ __launch_bounds__(256) void imp_alpha_kernel(
    const float* __restrict__ x,
    const float* __restrict__ Wimp, const float* __restrict__ bimp,
    const float* __restrict__ Walpha, const float* __restrict__ balpha,
    const float* __restrict__ thr_p,
    float* __restrict__ spike, float* __restrict__ alpha) {
  int m = blockIdx.x;
  int tid = threadIdx.x;
  const float* xr = x + (size_t)m * E_;
  float part[17];
#pragma unroll
  for (int i = 0; i < 17; ++i) part[i] = 0.f;
  for (int e = tid; e < E_; e += 256) {
    float xv = xr[e];
    part[16] += xv * Wimp[e];
#pragma unroll
    for (int h = 0; h < 16; ++h) part[h] += xv * Walpha[h * E_ + e];
  }
  __shared__ float red[17][4];
  int lane = tid & 63, wv = tid >> 6;
#pragma unroll
  for (int i = 0; i < 17; ++i) {
    float v = part[i];
    for (int off = 32; off > 0; off >>= 1) v += __shfl_down(v, off, 64);
    if (lane == 0) red[i][wv] = v;
  }
  __syncthreads();
  if (tid < 17) {
    float v = red[tid][0] + red[tid][1] + red[tid][2] + red[tid][3];
    if (tid == 16) {
      float z = v + bimp[0];
      float sig = 1.f / (1.f + expf(-z));
      spike[m] = (sig > thr_p[0]) ? 1.f : 0.f;
    } else {
      float z = v + balpha[tid];
      float a = 1.f / (1.f + expf(-z));
      int b = m >> 10, t = m & (T_ - 1);
      alpha[((size_t)(b * H_ + tid)) * T_ + t] = a;
    }
  }
}

// ---------------- K1: QKV GEMM — bf16 MFMA, 128x128 tile ----------------
__global__ __launch_bounds__(256) void qkv_gemm_kernel(
    const __bf16* __restrict__ A, const __bf16* __restrict__ Bm,
    const float* __restrict__ bias,
    __bf16* __restrict__ q, __bf16* __restrict__ k, __bf16* __restrict__ v) {
  __shared__ __bf16 As[128 * 32];
  __shared__ __bf16 Bs[128 * 32];
  const int K = E_;
  int tid = threadIdx.x;
  int w = tid >> 6, lane = tid & 63, lr = lane & 15, g = lane >> 4;
  int m0 = blockIdx.y * 128, n0 = blockIdx.x * 128;
  int wr = (w >> 1) * 64, wc = (w & 1) * 64;

  int task0 = tid, task1 = tid + 256;
  int r0s = task0 >> 2, c0s = task0 & 3;
  int r1s = task1 >> 2, c1s = task1 & 3;
  const __bf16* gA0 = A + (size_t)(m0 + r0s) * K + c0s * 8;
  const __bf16* gA1 = A + (size_t)(m0 + r1s) * K + c1s * 8;
  const __bf16* gB0 = Bm + (size_t)(n0 + r0s) * K + c0s * 8;
  const __bf16* gB1 = Bm + (size_t)(n0 + r1s) * K + c1s * 8;
  __bf16* lA0 = As + task0 * 8;
  __bf16* lA1 = As + task1 * 8;
  __bf16* lB0 = Bs + task0 * 8;
  __bf16* lB1 = Bs + task1 * 8;

  f32x4 acc[4][4];
#pragma unroll
  for (int i = 0; i < 4; ++i)
#pragma unroll
    for (int j = 0; j < 4; ++j) acc[i][j] = (f32x4){0.f, 0.f, 0.f, 0.f};

  for (int k0 = 0; k0 < K; k0 += 32) {
    gload_lds16(gA0, lA0); gload_lds16(gA1, lA1);
    gload_lds16(gB0, lB0); gload_lds16(gB1, lB1);
    gA0 += 32; gA1 += 32; gB0 += 32; gB1 += 32;
    __syncthreads();
    bf16x8 af[4], bf[4];
#pragma unroll
    for (int i = 0; i < 4; ++i) af[i] = *(bf16x8*)&As[(wr + i * 16 + lr) * 32 + g * 8];
#pragma unroll
    for (int j = 0; j < 4; ++j) bf[j] = *(bf16x8*)&Bs[(wc + j * 16 + lr) * 32 + g * 8];
#pragma unroll
    for (int i = 0; i < 4; ++i)
#pragma unroll
      for (int j = 0; j < 4; ++j)
        acc[i][j] = __builtin_amdgcn_mfma_f32_16x16x32_bf16(af[i], bf[j], acc[i][j], 0, 0, 0);
    __syncthreads();
  }

#pragma unroll
  for (int i = 0; i < 4; ++i) {
#pragma unroll
    for (int r = 0; r < 4; ++r) {
      int m = m0 + wr + i * 16 + g * 4 + r;
      int b = m >> 10, t = m & (T_ - 1);
#pragma unroll
      for (int j = 0; j < 4; ++j) {
        int n = n0 + wc + j * 16 + lr;
        float val = acc[i][j][r] + bias[n];
        int comp = n >> 10, h = (n >> 6) & 15, d = n & 63;
        __bf16* dst = (comp == 0) ? q : ((comp == 1) ? k : v);
        dst[(((size_t)(b * H_ + h)) * T_ + t) * 64 + d] = (__bf16)val;
      }
    }
  }
}

// ---------------- K2: hyperboloid map (bf16 in/out, f32 math) ----------------
__global__ __launch_bounds__(256) void hyp_kernel(
    const __bf16* __restrict__ q, const __bf16* __restrict__ k,
    const float* __restrict__ qk_scale_p,
    __bf16* __restrict__ qh, __bf16* __restrict__ khn) {
  int wid = blockIdx.x * 4 + (threadIdx.x >> 6);
  int lane = threadIdx.x & 63;
  int is_k = wid >> 15;
  int row = wid & 32767;
  const __bf16* src = (is_k ? k : q) + (size_t)row * 64;
  float u = (float)src[lane];
  float nsq = u * u;
#pragma unroll
  for (int off = 32; off > 0; off >>= 1) nsq += __shfl_xor(nsq, off, 64);
  float norm = fmaxf(sqrtf(nsq), 1e-12f);
  float ss = 1.5f / (1.f + expf(-qk_scale_p[0]));
  float un = u / norm * ss;
  float s2 = un * un;
  float tot = s2;
#pragma unroll
  for (int off = 32; off > 0; off >>= 1) tot += __shfl_xor(tot, off, 64);
  float un0 = __shfl(un, 0, 64);
  float mink = tot - 2.f * un0 * un0;
  float nomin = sqrtf(fmaxf(mink, 1e-8f));
  float sc = sinhf(nomin) / nomin;
  float r = sc * un;
  float sp2 = (lane == 0) ? 0.f : r * r;
  float sps = sp2;
#pragma unroll
  for (int off = 32; off > 0; off >>= 1) sps += __shfl_xor(sps, off, 64);
  float tm = sqrtf(1.f + sps);
  float outv = (lane == 0) ? tm : r;
  if (is_k && lane != 0) outv = -outv;  // fold Minkowski sign
  (is_k ? khn : qh)[(size_t)row * 64 + lane] = (__bf16)outv;
}

// ---------------- K2b: V transpose -> vt[bh][d][t] ----------------
__global__ __launch_bounds__(256) void vtr_kernel(
    const __bf16* __restrict__ v, __bf16* __restrict__ vt) {
  __shared__ __bf16 tile[64][65];
  int bh = blockIdx.x >> 4;
  int s0 = (blockIdx.x & 15) * 64;
  int tid = threadIdx.x;
#pragma unroll
  for (int it = 0; it < 2; ++it) {
    int task = tid + it * 256;
    int r = task >> 3, c = (task & 7) * 8;
    bf16x8 a = *(const bf16x8*)(v + ((size_t)bh * T_ + s0 + r) * 64 + c);
#pragma unroll
    for (int i = 0; i < 8; ++i) tile[r][c + i] = a[i];
  }
  __syncthreads();
#pragma unroll
  for (int it = 0; it < 2; ++it) {
    int task = tid + it * 256;
    int dd = task >> 3, sc = (task & 7) * 8;
    bf16x8 o;
#pragma unroll
    for (int i = 0; i < 8; ++i) o[i] = tile[sc + i][dd];
    *(bf16x8*)(vt + ((size_t)bh * 64 + dd) * T_ + s0 + sc) = o;
  }
}

// ---------------- K3: wave-independent dual-geometry flash attention ----------------
// One wave per (bh, 16-row q-tile, s-parity half). No barriers: K/KH/VT
// B-fragments read straight from global (L2-resident per bh), P transposed
// through a private per-wave swizzled LDS slab (wave-synchronous).
// Partials (m, l, acc) written for the merge kernel.
__global__ __launch_bounds__(256) void attn_kernel(
    const __bf16* __restrict__ q, const __bf16* __restrict__ k,
    const __bf16* __restrict__ qh, const __bf16* __restrict__ khn,
    const __bf16* __restrict__ vt,
    const float* __restrict__ alpha, const float* __restrict__ log_k,
    __bf16* __restrict__ pacc, float* __restrict__ pml) {
  __shared__ __bf16 pslab_all[4][16 * 64];
  int tid = threadIdx.x;
  int w = tid >> 6, lane = tid & 63;
  int wid = blockIdx.x * 4 + w;          // 0..4095
  int bh = wid & 31;
  int rest = wid >> 5;                   // 0..127
  int half = rest & 1;
  int qt = rest >> 1;                    // 0..63
  int h = bh & 15;
  int lr = lane & 15, g = lane >> 4;
  int n_st = (qt >> 2) + 1;
  const size_t base = (size_t)bh * T_ * 64;
  const size_t vtb = (size_t)bh * 64 * T_;
  __bf16* pslab = pslab_all[w];

  // Q / QH A-fragments straight from global (L2-hot)
  const __bf16* qrow = q + base + (size_t)(qt * 16 + lr) * 64;
  const __bf16* qhrow = qh + base + (size_t)(qt * 16 + lr) * 64;
  bf16x8 aq0 = *(const bf16x8*)(qrow + g * 8);
  bf16x8 aq1 = *(const bf16x8*)(qrow + 32 + g * 8);
  bf16x8 ah0 = *(const bf16x8*)(qhrow + g * 8);
  bf16x8 ah1 = *(const bf16x8*)(qhrow + 32 + g * 8);

  float curv = log1pf(expf(log_k[h])) + 1e-6f;
  float hc = 0.69314718056f / curv;      // ln2/curv (log2-domain)
  const float ec = 0.18033688f;          // 0.125 * log2(e)
  int tg[4]; float al[4];
#pragma unroll
  for (int r = 0; r < 4; ++r) {
    tg[r] = qt * 16 + g * 4 + r;
    al[r] = alpha[(size_t)bh * T_ + tg[r]];
  }

  float m_r[4] = {-1e30f, -1e30f, -1e30f, -1e30f};
  float l_r[4] = {0.f, 0.f, 0.f, 0.f};
  f32x4 acc[4];
#pragma unroll
  for (int n = 0; n < 4; ++n) acc[n] = (f32x4){0.f, 0.f, 0.f, 0.f};

  for (int st = half; st < n_st; st += 2) {
    int s0 = st * 64;
    bool diag = (st == n_st - 1);
    float pv[4][4];
    float pmax[4] = {-1e30f, -1e30f, -1e30f, -1e30f};
#pragma unroll
    for (int j = 0; j < 4; ++j) {
      if (diag && (s0 + j * 16 > qt * 16 + 15)) {   // wave-uniform full mask
#pragma unroll
        for (int r = 0; r < 4; ++r) pv[j][r] = -1e30f;
        continue;
      }
      const __bf16* kr = k + base + (size_t)(s0 + j * 16 + lr) * 64;
      const __bf16* khr = khn + base + (size_t)(s0 + j * 16 + lr) * 64;
      bf16x8 bk0 = *(const bf16x8*)(kr + g * 8);
      bf16x8 bk1 = *(const bf16x8*)(kr + 32 + g * 8);
      f32x4 z = {0.f, 0.f, 0.f, 0.f};
      z = __builtin_amdgcn_mfma_f32_16x16x32_bf16(aq0, bk0, z, 0, 0, 0);
      f32x4 se = __builtin_amdgcn_mfma_f32_16x16x32_bf16(aq1, bk1, z, 0, 0, 0);
      bf16x8 bh0 = *(const bf16x8*)(khr + g * 8);
      bf16x8 bh1 = *(const bf16x8*)(khr + 32 + g * 8);
      f32x4 z2 = {0.f, 0.f, 0.f, 0.f};
      z2 = __builtin_amdgcn_mfma_f32_16x16x32_bf16(ah0, bh0, z2, 0, 0, 0);
      f32x4 sh = __builtin_amdgcn_mfma_f32_16x16x32_bf16(ah1, bh1, z2, 0, 0, 0);
      int sg = s0 + j * 16 + lr;
#pragma unroll
      for (int r = 0; r < 4; ++r) {
        float sc_e = se[r] * ec;
        float md = fmaxf(sh[r], 1.0f + 1e-6f);
        float l2 = __log2f(md + sqrtf(fmaf(md, md, -1.f)));  // acosh, log2 units
        float t = fmaf(l2 * l2, hc, sc_e);
        float s = fmaf(-al[r], t, sc_e);                      // (1-a)e - a*h
        if (diag && sg > tg[r]) s = -1e30f;
        pv[j][r] = s;
        pmax[r] = fmaxf(pmax[r], s);
      }
    }
    // online softmax (log2 domain), row groups live in 16-lane slices
#pragma unroll
    for (int r = 0; r < 4; ++r) {
      float mx = pmax[r];
      mx = fmaxf(mx, __shfl_xor(mx, 1, 64));
      mx = fmaxf(mx, __shfl_xor(mx, 2, 64));
      mx = fmaxf(mx, __shfl_xor(mx, 4, 64));
      mx = fmaxf(mx, __shfl_xor(mx, 8, 64));
      float mn = fmaxf(m_r[r], mx);
      float fac = exp2f(m_r[r] - mn);
      m_r[r] = mn;
      float ls = 0.f;
#pragma unroll
      for (int j = 0; j < 4; ++j) { pv[j][r] = exp2f(pv[j][r] - mn); ls += pv[j][r]; }
      ls += __shfl_xor(ls, 1, 64);
      ls += __shfl_xor(ls, 2, 64);
      ls += __shfl_xor(ls, 4, 64);
      ls += __shfl_xor(ls, 8, 64);
      l_r[r] = l_r[r] * fac + ls;
#pragma unroll
      for (int n = 0; n < 4; ++n) acc[n][r] *= fac;
    }
    // P transpose through private slab (wave-synchronous: lgkmcnt only)
#pragma unroll
    for (int j = 0; j < 4; ++j)
#pragma unroll
      for (int r = 0; r < 4; ++r)
        *(__bf16*)ldsp(pslab, g * 4 + r, (j * 16 + lr) * 2) = (__bf16)pv[j][r];
    bf16x8 ap0 = *(bf16x8*)ldsp(pslab, lr, g * 16);
    bf16x8 ap1 = *(bf16x8*)ldsp(pslab, lr, 64 + g * 16);
    // PV: B-fragments from vt (global, L2-hot)
#pragma unroll
    for (int n = 0; n < 4; ++n) {
      const __bf16* vr = vt + vtb + (size_t)(n * 16 + lr) * T_ + s0;
      bf16x8 bv0 = *(const bf16x8*)(vr + g * 8);
      bf16x8 bv1 = *(const bf16x8*)(vr + 32 + g * 8);
      acc[n] = __builtin_amdgcn_mfma_f32_16x16x32_bf16(ap0, bv0, acc[n], 0, 0, 0);
      acc[n] = __builtin_amdgcn_mfma_f32_16x16x32_bf16(ap1, bv1, acc[n], 0, 0, 0);
    }
  }

  // write partials
  int pidx = ((bh << 6) + qt) * 2 + half;
  __bf16* pa = pacc + (size_t)pidx * 1024;
#pragma unroll
  for (int n = 0; n < 4; ++n)
#pragma unroll
    for (int r = 0; r < 4; ++r)
      pa[(g * 4 + r) * 64 + n * 16 + lr] = (__bf16)acc[n][r];
  if (lr == 0) {
#pragma unroll
    for (int r = 0; r < 4; ++r) {
      pml[(size_t)pidx * 32 + g * 4 + r] = m_r[r];
      pml[(size_t)pidx * 32 + 16 + g * 4 + r] = l_r[r];
    }
  }
}

// ---------------- K3b: merge halves + spike gate -> yw (bf16) ----------------
__global__ __launch_bounds__(256) void merge_kernel(
    const __bf16* __restrict__ pacc, const float* __restrict__ pml,
    const float* __restrict__ spike, __bf16* __restrict__ yw) {
  int tid = threadIdx.x;
  int w = tid >> 6, lane = tid & 63;
  int wid = blockIdx.x * 4 + w;          // 0..2047
  int bh = wid & 31;
  int qt = wid >> 5;                     // 0..63
  int b = bh >> 4, h = bh & 15;
  size_t i1 = ((size_t)(bh << 6) + qt) * 2;
  size_t i2 = i1 + 1;
  const __bf16* a1 = pacc + i1 * 1024;
  const __bf16* a2 = pacc + i2 * 1024;
#pragma unroll 4
  for (int row = 0; row < 16; ++row) {
    float m1 = pml[i1 * 32 + row], l1 = pml[i1 * 32 + 16 + row];
    float m2 = pml[i2 * 32 + row], l2 = pml[i2 * 32 + 16 + row];
    float mm = fmaxf(m1, m2);
    float f1 = exp2f(m1 - mm), f2 = exp2f(m2 - mm);
    float l = l1 * f1 + l2 * f2;
    int t = qt * 16 + row;
    float iv = spike[(size_t)b * T_ + t] / l;
    float val = ((float)a1[row * 64 + lane] * f1 +
                 (float)a2[row * 64 + lane] * f2) * iv;
    yw[(size_t)(b * T_ + t) * E_ + h * 64 + lane] = (__bf16)val;
  }
}

// ---------------- K4: output projection — bf16 MFMA, f32 out ----------------
__global__ __launch_bounds__(256) void out_gemm_kernel(
    const __bf16* __restrict__ A, const __bf16* __restrict__ Bm,
    const float* __restrict__ bias, float* __restrict__ outp) {
  __shared__ __bf16 As[128 * 32];
  __shared__ __bf16 Bs[128 * 32];
  const int K = E_;
  int tid = threadIdx.x;
  int w = tid >> 6, lane = tid & 63, lr = lane & 15, g = lane >> 4;
  int m0 = blockIdx.y * 128, n0 = blockIdx.x * 128;
  int wr = (w >> 1) * 64, wc = (w & 1) * 64;

  int task0 = tid, task1 = tid + 256;
  int r0s = task0 >> 2, c0s = task0 & 3;
  int r1s = task1 >> 2, c1s = task1 & 3;
  const __bf16* gA0 = A + (size_t)(m0 + r0s) * K + c0s * 8;
  const __bf16* gA1 = A + (size_t)(m0 + r1s) * K + c1s * 8;
  const __bf16* gB0 = Bm + (size_t)(n0 + r0s) * K + c0s * 8;
  const __bf16* gB1 = Bm + (size_t)(n0 + r1s) * K + c1s * 8;
  __bf16* lA0 = As + task0 * 8;
  __bf16* lA1 = As + task1 * 8;
  __bf16* lB0 = Bs + task0 * 8;
  __bf16* lB1 = Bs + task1 * 8;

  f32x4 acc[4][4];
#pragma unroll
  for (int i = 0; i < 4; ++i)
#pragma unroll
    for (int j = 0; j < 4; ++j) acc[i][j] = (f32x4){0.f, 0.f, 0.f, 0.f};

  for (int k0 = 0; k0 < K; k0 += 32) {
    gload_lds16(gA0, lA0); gload_lds16(gA1, lA1);
    gload_lds16(gB0, lB0); gload_lds16(gB1, lB1);
    gA0 += 32; gA1 += 32; gB0 += 32; gB1 += 32;
    __syncthreads();
    bf16x8 af[4], bf[4];
#pragma unroll
    for (int i = 0; i < 4; ++i) af[i] = *(bf16x8*)&As[(wr + i * 16 + lr) * 32 + g * 8];
#pragma unroll
    for (int j = 0; j < 4; ++j) bf[j] = *(bf16x8*)&Bs[(wc + j * 16 + lr) * 32 + g * 8];
#pragma unroll
    for (int i = 0; i < 4; ++i)
#pragma unroll
      for (int j = 0; j < 4; ++j)
        acc[i][j] = __builtin_amdgcn_mfma_f32_16x16x32_bf16(af[i], bf[j], acc[i][j], 0, 0, 0);
    __syncthreads();
  }

#pragma unroll
  for (int i = 0; i < 4; ++i) {
#pragma unroll
    for (int r = 0; r < 4; ++r) {
      int m = m0 + wr + i * 16 + g * 4 + r;
#pragma unroll
      for (int j = 0; j < 4; ++j) {
        int n = n0 + wc + j * 16 + lr;
        outp[(size_t)m * E_ + n] = acc[i][j][r] + bias[n];
      }
    }
  }
}

extern "C" void kernel_launch(void* const* d_in, const int* in_sizes, int n_in,
                              void* d_out, int out_size, void* d_ws, size_t ws_size,
                              hipStream_t stream) {
  const float* x      = (const float*)d_in[0];
  const float* Wqkv   = (const float*)d_in[1];
  const float* bqkv   = (const float*)d_in[2];
  const float* Wout   = (const float*)d_in[3];
  const float* bout   = (const float*)d_in[4];
  const float* Wimp   = (const float*)d_in[5];
  const float* bimp   = (const float*)d_in[6];
  const float* Walpha = (const float*)d_in[7];
  const float* balpha = (const float*)d_in[8];
  const float* thr    = (const float*)d_in[9];
  const float* log_k  = (const float*)d_in[10];
  const float* qk_sc  = (const float*)d_in[11];
  float* out = (float*)d_out;

  char* ws = (char*)d_ws;
  size_t off = 0;
  auto alloc = [&](size_t bytes) -> void* {
    void* p = (void*)(ws + off);
    off += (bytes + 255) & ~(size_t)255;
    return p;
  };
  const size_t qkv_elems = (size_t)B_ * H_ * T_ * D_;
  __bf16* xb    = (__bf16*)alloc((size_t)M_ * E_ * 2);      // dead after qkv_gemm
  __bf16* Wqkvb = (__bf16*)alloc((size_t)3 * E_ * E_ * 2);  // dead after qkv_gemm
  __bf16* Woutb = (__bf16*)alloc((size_t)E_ * E_ * 2);
  __bf16* q   = (__bf16*)alloc(qkv_elems * 2);
  __bf16* k   = (__bf16*)alloc(qkv_elems * 2);
  __bf16* v   = (__bf16*)alloc(qkv_elems * 2);
  __bf16* qh  = (__bf16*)alloc(qkv_elems * 2);
  __bf16* khn = (__bf16*)alloc(qkv_elems * 2);
  __bf16* vt  = (__bf16*)alloc(qkv_elems * 2);
  __bf16* yw  = (__bf16*)alloc((size_t)M_ * E_ * 2);
  float* alphaw = (float*)alloc((size_t)B_ * H_ * T_ * sizeof(float));
  float* spikew = (float*)alloc((size_t)M_ * sizeof(float));
  float* pml    = (float*)alloc((size_t)4096 * 32 * sizeof(float));
  // pacc (8 MB) aliases xb+Wqkvb (10 MB), both dead before attn runs
  __bf16* pacc = (__bf16*)ws;

  conv_kernel<<<1024, 256, 0, stream>>>(x, Wqkv, Wout, xb, Wqkvb, Woutb);
  imp_alpha_kernel<<<M_, 256, 0, stream>>>(x, Wimp, bimp, Walpha, balpha, thr,
                                           spikew, alphaw);
  qkv_gemm_kernel<<<dim3(24, 16), 256, 0, stream>>>(xb, Wqkvb, bqkv, q, k, v);
  hyp_kernel<<<(2 * B_ * H_ * T_) / 4, 256, 0, stream>>>(q, k, qk_sc, qh, khn);
  vtr_kernel<<<B_ * H_ * (T_ / 64), 256, 0, stream>>>(v, vt);
  attn_kernel<<<1024, 256, 0, stream>>>(q, k, qh, khn, vt, alphaw, log_k,
                                        pacc, pml);
  merge_kernel<<<512, 256, 0, stream>>>(pacc, pml, spikew, yw);
  out_gemm_kernel<<<dim3(8, 16), 256, 0, stream>>>(yw, Woutb, bout, out);
}

// Round 7
// 153.025 us; speedup vs baseline: 1.1986x; 1.1986x over previous
//
#include <hip/hip_runtime.h>
#include <math.h>

#define B_ 2
#define T_ 1024
#define E_ 1024
#define H_ 16
#define D_ 64
#define M_ (B_*T_)

typedef __bf16 bf16x8 __attribute__((ext_vector_type(8)));
typedef __bf16 bf16x4 __attribute__((ext_vector_type(4)));
typedef float f32x4 __attribute__((ext_vector_type(4)));

// swizzled LDS addressing: row-major [rows][128 bytes], byte ^= (row&7)<<4
__device__ __forceinline__ void* ldsp(__bf16* base, int row, int byte) {
  return (char*)base + row * 128 + (byte ^ ((row & 7) << 4));
}

__device__ __forceinline__ void gload_lds16(const void* g, void* l) {
  __builtin_amdgcn_global_load_lds((const __attribute__((address_space(1))) void*)g,
                                   (__attribute__((address_space(3))) void*)l, 16, 0, 0);
}

// ---------------- K-1: f32 -> bf16 conversions (x, Wqkv, Wout) ----------------
#define XV4 524288     // (2*1024*1024)/4
#define WQV4 786432    // (3072*1024)/4
#define WOV4 262144    // (1024*1024)/4
#define TOTV4 (XV4 + WQV4 + WOV4)
__global__ __launch_bounds__(256) void conv_kernel(
    const float* __restrict__ x, const float* __restrict__ Wqkv,
    const float* __restrict__ Wout,
    __bf16* __restrict__ xb, __bf16* __restrict__ Wqkvb, __bf16* __restrict__ Woutb) {
  for (size_t i = (size_t)blockIdx.x * blockDim.x + threadIdx.x; i < TOTV4;
       i += (size_t)gridDim.x * blockDim.x) {
    const float4* src; __bf16* dst; size_t off;
    if (i < XV4)            { src = (const float4*)x;    dst = xb;    off = i; }
    else if (i < XV4+WQV4)  { src = (const float4*)Wqkv; dst = Wqkvb; off = i - XV4; }
    else                    { src = (const float4*)Wout; dst = Woutb; off = i - XV4 - WQV4; }
    float4 val = src[off];
    bf16x4 o = {(__bf16)val.x, (__bf16)val.y, (__bf16)val.z, (__bf16)val.w};
    *(bf16x4*)(dst + off * 4) = o;
  }
}

// ---------------- K0: importance (spike) + alpha (f32 — sign decision!) ----------------
__global__ __launch_bounds__(256) void imp_alpha_kernel(
    const float* __restrict__ x,
    const float* __restrict__ Wimp, const float* __restrict__ bimp,
    const float* __restrict__ Walpha, const float* __restrict__ balpha,
    const float* __restrict__ thr_p,
    float* __restrict__ spike, float* __restrict__ alpha) {
  int m = blockIdx.x;
  int tid = threadIdx.x;
  const float* xr = x + (size_t)m * E_;
  float part[17];
#pragma unroll
  for (int i = 0; i < 17; ++i) part[i] = 0.f;
  for (int e = tid; e < E_; e += 256) {
    float xv = xr[e];
    part[16] += xv * Wimp[e];
#pragma unroll
    for (int h = 0; h < 16; ++h) part[h] += xv * Walpha[h * E_ + e];
  }
  __shared__ float red[17][4];
  int lane = tid & 63, wv = tid >> 6;
#pragma unroll
  for (int i = 0; i < 17; ++i) {
    float v = part[i];
    for (int off = 32; off > 0; off >>= 1) v += __shfl_down(v, off, 64);
    if (lane == 0) red[i][wv] = v;
  }
  __syncthreads();
  if (tid < 17) {
    float v = red[tid][0] + red[tid][1] + red[tid][2] + red[tid][3];
    if (tid == 16) {
      float z = v + bimp[0];
      float sig = 1.f / (1.f + expf(-z));
      spike[m] = (sig > thr_p[0]) ? 1.f : 0.f;
    } else {
      float z = v + balpha[tid];
      float a = 1.f / (1.f + expf(-z));
      int b = m >> 10, t = m & (T_ - 1);
      alpha[((size_t)(b * H_ + tid)) * T_ + t] = a;
    }
  }
}

// ---------------- K1: QKV GEMM — bf16 MFMA, 128x128 tile ----------------
__global__ __launch_bounds__(256) void qkv_gemm_kernel(
    const __bf16* __restrict__ A, const __bf16* __restrict__ Bm,
    const float* __restrict__ bias,
    __bf16* __restrict__ q, __bf16* __restrict__ k, __bf16* __restrict__ v) {
  __shared__ __bf16 As[128 * 32];
  __shared__ __bf16 Bs[128 * 32];
  const int K = E_;
  int tid = threadIdx.x;
  int w = tid >> 6, lane = tid & 63, lr = lane & 15, g = lane >> 4;
  int m0 = blockIdx.y * 128, n0 = blockIdx.x * 128;
  int wr = (w >> 1) * 64, wc = (w & 1) * 64;

  int task0 = tid, task1 = tid + 256;
  int r0s = task0 >> 2, c0s = task0 & 3;
  int r1s = task1 >> 2, c1s = task1 & 3;
  const __bf16* gA0 = A + (size_t)(m0 + r0s) * K + c0s * 8;
  const __bf16* gA1 = A + (size_t)(m0 + r1s) * K + c1s * 8;
  const __bf16* gB0 = Bm + (size_t)(n0 + r0s) * K + c0s * 8;
  const __bf16* gB1 = Bm + (size_t)(n0 + r1s) * K + c1s * 8;
  __bf16* lA0 = As + task0 * 8;
  __bf16* lA1 = As + task1 * 8;
  __bf16* lB0 = Bs + task0 * 8;
  __bf16* lB1 = Bs + task1 * 8;

  f32x4 acc[4][4];
#pragma unroll
  for (int i = 0; i < 4; ++i)
#pragma unroll
    for (int j = 0; j < 4; ++j) acc[i][j] = (f32x4){0.f, 0.f, 0.f, 0.f};

  for (int k0 = 0; k0 < K; k0 += 32) {
    gload_lds16(gA0, lA0); gload_lds16(gA1, lA1);
    gload_lds16(gB0, lB0); gload_lds16(gB1, lB1);
    gA0 += 32; gA1 += 32; gB0 += 32; gB1 += 32;
    __syncthreads();
    bf16x8 af[4], bf[4];
#pragma unroll
    for (int i = 0; i < 4; ++i) af[i] = *(bf16x8*)&As[(wr + i * 16 + lr) * 32 + g * 8];
#pragma unroll
    for (int j = 0; j < 4; ++j) bf[j] = *(bf16x8*)&Bs[(wc + j * 16 + lr) * 32 + g * 8];
#pragma unroll
    for (int i = 0; i < 4; ++i)
#pragma unroll
      for (int j = 0; j < 4; ++j)
        acc[i][j] = __builtin_amdgcn_mfma_f32_16x16x32_bf16(af[i], bf[j], acc[i][j], 0, 0, 0);
    __syncthreads();
  }

#pragma unroll
  for (int i = 0; i < 4; ++i) {
#pragma unroll
    for (int r = 0; r < 4; ++r) {
      int m = m0 + wr + i * 16 + g * 4 + r;
      int b = m >> 10, t = m & (T_ - 1);
#pragma unroll
      for (int j = 0; j < 4; ++j) {
        int n = n0 + wc + j * 16 + lr;
        float val = acc[i][j][r] + bias[n];
        int comp = n >> 10, h = (n >> 6) & 15, d = n & 63;
        __bf16* dst = (comp == 0) ? q : ((comp == 1) ? k : v);
        dst[(((size_t)(b * H_ + h)) * T_ + t) * 64 + d] = (__bf16)val;
      }
    }
  }
}

// ---------------- K2: hyperboloid map (bf16 in/out, f32 math) ----------------
__global__ __launch_bounds__(256) void hyp_kernel(
    const __bf16* __restrict__ q, const __bf16* __restrict__ k,
    const float* __restrict__ qk_scale_p,
    __bf16* __restrict__ qh, __bf16* __restrict__ khn) {
  int wid = blockIdx.x * 4 + (threadIdx.x >> 6);
  int lane = threadIdx.x & 63;
  int is_k = wid >> 15;
  int row = wid & 32767;
  const __bf16* src = (is_k ? k : q) + (size_t)row * 64;
  float u = (float)src[lane];
  float nsq = u * u;
#pragma unroll
  for (int off = 32; off > 0; off >>= 1) nsq += __shfl_xor(nsq, off, 64);
  float norm = fmaxf(sqrtf(nsq), 1e-12f);
  float ss = 1.5f / (1.f + expf(-qk_scale_p[0]));
  float un = u / norm * ss;
  float s2 = un * un;
  float tot = s2;
#pragma unroll
  for (int off = 32; off > 0; off >>= 1) tot += __shfl_xor(tot, off, 64);
  float un0 = __shfl(un, 0, 64);
  float mink = tot - 2.f * un0 * un0;
  float nomin = sqrtf(fmaxf(mink, 1e-8f));
  float sc = sinhf(nomin) / nomin;
  float r = sc * un;
  float sp2 = (lane == 0) ? 0.f : r * r;
  float sps = sp2;
#pragma unroll
  for (int off = 32; off > 0; off >>= 1) sps += __shfl_xor(sps, off, 64);
  float tm = sqrtf(1.f + sps);
  float outv = (lane == 0) ? tm : r;
  if (is_k && lane != 0) outv = -outv;  // fold Minkowski sign
  (is_k ? khn : qh)[(size_t)row * 64 + lane] = (__bf16)outv;
}

// ---------------- K3: split-s staged dual-geometry flash attention ----------------
// grid 1024 = 32 bh x 16 qt x 2 s-halves; each block <= 8 s-tiles (serial
// chain halved vs r3). LDS 32KB (k/kh/vt/p) -> 5 blocks/CU capacity, all
// 1024 resident. Q/QH A-frags direct from global. bh clustered per XCD.
__global__ __launch_bounds__(256) void attn_kernel(
    const __bf16* __restrict__ q, const __bf16* __restrict__ k, const __bf16* __restrict__ v,
    const __bf16* __restrict__ qh, const __bf16* __restrict__ khn,
    const float* __restrict__ alpha, const float* __restrict__ log_k,
    __bf16* __restrict__ pacc, float* __restrict__ pml) {
  __shared__ __bf16 k_s[64 * 64];
  __shared__ __bf16 kh_s[64 * 64];
  __shared__ __bf16 vt_s[64 * 64];
  __shared__ __bf16 p_s[64 * 64];

  int bid = blockIdx.x;
  int bh = ((bid & 7) << 2) | ((bid >> 3) & 3);  // 4 bh per XCD (L2 locality)
  int rest = bid >> 5;                           // 0..31
  int qt = rest & 15;
  int half = rest >> 4;
  int h = bh & 15;
  int t0 = qt * 64;
  int n_st = qt + 1;
  int nh = (n_st + 1) >> 1;
  int s_beg = half ? nh : 0;
  int s_end = half ? n_st : nh;

  int tid = threadIdx.x;
  int w = tid >> 6, lane = tid & 63;
  int lr = lane & 15, g = lane >> 4;
  int trow = w * 16;
  const size_t base = (size_t)bh * T_ * 64;

  // Q/QH A-fragments straight from global (L2-hot)
  const __bf16* qrow = q + base + (size_t)(t0 + trow + lr) * 64;
  const __bf16* qhrow = qh + base + (size_t)(t0 + trow + lr) * 64;
  bf16x8 aq0 = *(const bf16x8*)(qrow + g * 8);
  bf16x8 aq1 = *(const bf16x8*)(qrow + 32 + g * 8);
  bf16x8 ah0 = *(const bf16x8*)(qhrow + g * 8);
  bf16x8 ah1 = *(const bf16x8*)(qhrow + 32 + g * 8);

  float curv = log1pf(expf(log_k[h])) + 1e-6f;
  float hc = 0.69314718056f / curv;        // ln2/curv (log2-domain)
  const float ec = 0.18033688f;            // 0.125 * log2(e)
  int tg[4]; float al[4];
#pragma unroll
  for (int r = 0; r < 4; ++r) {
    tg[r] = t0 + trow + g * 4 + r;
    al[r] = alpha[(size_t)bh * T_ + tg[r]];
  }

  float m_r[4] = {-1e30f, -1e30f, -1e30f, -1e30f};
  float l_r[4] = {0.f, 0.f, 0.f, 0.f};
  f32x4 acc[4];
#pragma unroll
  for (int n = 0; n < 4; ++n) acc[n] = (f32x4){0.f, 0.f, 0.f, 0.f};

  for (int st = s_beg; st < s_end; ++st) {
    int s0 = st * 64;
    bool diag = (st == n_st - 1);
    __syncthreads();
    // ---- stage K, KH, V^T (cooperative) ----
#pragma unroll
    for (int it = 0; it < 2; ++it) {
      int task = tid + it * 256;
      int row = task >> 3, cj = task & 7;
      bf16x8 a = *(const bf16x8*)(k + base + (size_t)(s0 + row) * 64 + cj * 8);
      bf16x8 c = *(const bf16x8*)(khn + base + (size_t)(s0 + row) * 64 + cj * 8);
      *(bf16x8*)ldsp(k_s, row, cj * 16) = a;
      *(bf16x8*)ldsp(kh_s, row, cj * 16) = c;
    }
#pragma unroll
    for (int it = 0; it < 2; ++it) {
      int task = tid + it * 256;
      int srow = task & 63, dc = task >> 6;
      bf16x8 a = *(const bf16x8*)(v + base + (size_t)(s0 + srow) * 64 + dc * 8);
#pragma unroll
      for (int i = 0; i < 8; ++i)
        *(__bf16*)ldsp(vt_s, dc * 8 + i, srow * 2) = a[i];
    }
    __syncthreads();

    // ---- per-j: MFMA scores + blend (causal only on diagonal tile) ----
    float pv[4][4];
    float pmax[4] = {-1e30f, -1e30f, -1e30f, -1e30f};
#pragma unroll
    for (int j = 0; j < 4; ++j) {
      if (diag && (s0 + j * 16 > t0 + trow + 15)) {   // wave-uniform full mask
#pragma unroll
        for (int r = 0; r < 4; ++r) pv[j][r] = -1e30f;
        continue;
      }
      bf16x8 bk0 = *(bf16x8*)ldsp(k_s, j * 16 + lr, g * 16);
      bf16x8 bk1 = *(bf16x8*)ldsp(k_s, j * 16 + lr, 64 + g * 16);
      f32x4 z = {0.f, 0.f, 0.f, 0.f};
      z = __builtin_amdgcn_mfma_f32_16x16x32_bf16(aq0, bk0, z, 0, 0, 0);
      f32x4 se = __builtin_amdgcn_mfma_f32_16x16x32_bf16(aq1, bk1, z, 0, 0, 0);
      bf16x8 bh0 = *(bf16x8*)ldsp(kh_s, j * 16 + lr, g * 16);
      bf16x8 bh1 = *(bf16x8*)ldsp(kh_s, j * 16 + lr, 64 + g * 16);
      f32x4 z2 = {0.f, 0.f, 0.f, 0.f};
      z2 = __builtin_amdgcn_mfma_f32_16x16x32_bf16(ah0, bh0, z2, 0, 0, 0);
      f32x4 sh = __builtin_amdgcn_mfma_f32_16x16x32_bf16(ah1, bh1, z2, 0, 0, 0);
      int sg = s0 + j * 16 + lr;
#pragma unroll
      for (int r = 0; r < 4; ++r) {
        float sc_e = se[r] * ec;
        float md = fmaxf(sh[r], 1.0f + 1e-6f);
        float l2 = __log2f(md + sqrtf(fmaf(md, md, -1.f)));  // acosh, log2 units
        float t = fmaf(l2 * l2, hc, sc_e);
        float s = fmaf(-al[r], t, sc_e);                      // (1-a)e - a*h
        if (diag && sg > tg[r]) s = -1e30f;
        pv[j][r] = s;
        pmax[r] = fmaxf(pmax[r], s);
      }
    }
    // ---- online softmax (log2 domain) ----
#pragma unroll
    for (int r = 0; r < 4; ++r) {
      float mx = pmax[r];
      mx = fmaxf(mx, __shfl_xor(mx, 1, 64));
      mx = fmaxf(mx, __shfl_xor(mx, 2, 64));
      mx = fmaxf(mx, __shfl_xor(mx, 4, 64));
      mx = fmaxf(mx, __shfl_xor(mx, 8, 64));
      float mn = fmaxf(m_r[r], mx);
      float fac = exp2f(m_r[r] - mn);
      m_r[r] = mn;
      float ls = 0.f;
#pragma unroll
      for (int j = 0; j < 4; ++j) { pv[j][r] = exp2f(pv[j][r] - mn); ls += pv[j][r]; }
      ls += __shfl_xor(ls, 1, 64);
      ls += __shfl_xor(ls, 2, 64);
      ls += __shfl_xor(ls, 4, 64);
      ls += __shfl_xor(ls, 8, 64);
      l_r[r] = l_r[r] * fac + ls;
#pragma unroll
      for (int n = 0; n < 4; ++n) acc[n][r] *= fac;
    }
    // ---- P transpose through wave-private p_s rows (no barrier needed) ----
#pragma unroll
    for (int j = 0; j < 4; ++j)
#pragma unroll
      for (int r = 0; r < 4; ++r)
        *(__bf16*)ldsp(p_s, trow + g * 4 + r, (j * 16 + lr) * 2) = (__bf16)pv[j][r];
    bf16x8 ap0 = *(bf16x8*)ldsp(p_s, trow + lr, g * 16);
    bf16x8 ap1 = *(bf16x8*)ldsp(p_s, trow + lr, 64 + g * 16);
#pragma unroll
    for (int n = 0; n < 4; ++n) {
      bf16x8 bv0 = *(bf16x8*)ldsp(vt_s, n * 16 + lr, g * 16);
      bf16x8 bv1 = *(bf16x8*)ldsp(vt_s, n * 16 + lr, 64 + g * 16);
      acc[n] = __builtin_amdgcn_mfma_f32_16x16x32_bf16(ap0, bv0, acc[n], 0, 0, 0);
      acc[n] = __builtin_amdgcn_mfma_f32_16x16x32_bf16(ap1, bv1, acc[n], 0, 0, 0);
    }
  }

  // ---- write partials (merge kernel combines the two halves) ----
  int qt16 = (qt << 2) | w;              // 16-row tile index 0..63
  int pidx = ((bh << 6) + qt16) * 2 + half;
  __bf16* pa = pacc + (size_t)pidx * 1024;
#pragma unroll
  for (int n = 0; n < 4; ++n)
#pragma unroll
    for (int r = 0; r < 4; ++r)
      pa[(g * 4 + r) * 64 + n * 16 + lr] = (__bf16)acc[n][r];
  if (lr == 0) {
#pragma unroll
    for (int r = 0; r < 4; ++r) {
      pml[(size_t)pidx * 32 + g * 4 + r] = m_r[r];
      pml[(size_t)pidx * 32 + 16 + g * 4 + r] = l_r[r];
    }
  }
}

// ---------------- K3b: merge halves + spike gate -> yw (bf16) ----------------
__global__ __launch_bounds__(256) void merge_kernel(
    const __bf16* __restrict__ pacc, const float* __restrict__ pml,
    const float* __restrict__ spike, __bf16* __restrict__ yw) {
  int tid = threadIdx.x;
  int w = tid >> 6, lane = tid & 63;
  int wid = blockIdx.x * 4 + w;          // 0..2047
  int bh = wid & 31;
  int qt = wid >> 5;                     // 0..63
  int b = bh >> 4, h = bh & 15;
  size_t i1 = ((size_t)(bh << 6) + qt) * 2;
  size_t i2 = i1 + 1;
  const __bf16* a1 = pacc + i1 * 1024;
  const __bf16* a2 = pacc + i2 * 1024;
#pragma unroll 4
  for (int row = 0; row < 16; ++row) {
    float m1 = pml[i1 * 32 + row], l1 = pml[i1 * 32 + 16 + row];
    float m2 = pml[i2 * 32 + row], l2 = pml[i2 * 32 + 16 + row];
    float mm = fmaxf(m1, m2);
    float f1 = exp2f(m1 - mm), f2 = exp2f(m2 - mm);
    float l = l1 * f1 + l2 * f2;
    int t = qt * 16 + row;
    float iv = spike[(size_t)b * T_ + t] / l;
    float val = ((float)a1[row * 64 + lane] * f1 +
                 (float)a2[row * 64 + lane] * f2) * iv;
    yw[(size_t)(b * T_ + t) * E_ + h * 64 + lane] = (__bf16)val;
  }
}

// ---------------- K4: output projection — bf16 MFMA, f32 out ----------------
__global__ __launch_bounds__(256) void out_gemm_kernel(
    const __bf16* __restrict__ A, const __bf16* __restrict__ Bm,
    const float* __restrict__ bias, float* __restrict__ outp) {
  __shared__ __bf16 As[128 * 32];
  __shared__ __bf16 Bs[128 * 32];
  const int K = E_;
  int tid = threadIdx.x;
  int w = tid >> 6, lane = tid & 63, lr = lane & 15, g = lane >> 4;
  int m0 = blockIdx.y * 128, n0 = blockIdx.x * 128;
  int wr = (w >> 1) * 64, wc = (w & 1) * 64;

  int task0 = tid, task1 = tid + 256;
  int r0s = task0 >> 2, c0s = task0 & 3;
  int r1s = task1 >> 2, c1s = task1 & 3;
  const __bf16* gA0 = A + (size_t)(m0 + r0s) * K + c0s * 8;
  const __bf16* gA1 = A + (size_t)(m0 + r1s) * K + c1s * 8;
  const __bf16* gB0 = Bm + (size_t)(n0 + r0s) * K + c0s * 8;
  const __bf16* gB1 = Bm + (size_t)(n0 + r1s) * K + c1s * 8;
  __bf16* lA0 = As + task0 * 8;
  __bf16* lA1 = As + task1 * 8;
  __bf16* lB0 = Bs + task0 * 8;
  __bf16* lB1 = Bs + task1 * 8;

  f32x4 acc[4][4];
#pragma unroll
  for (int i = 0; i < 4; ++i)
#pragma unroll
    for (int j = 0; j < 4; ++j) acc[i][j] = (f32x4){0.f, 0.f, 0.f, 0.f};

  for (int k0 = 0; k0 < K; k0 += 32) {
    gload_lds16(gA0, lA0); gload_lds16(gA1, lA1);
    gload_lds16(gB0, lB0); gload_lds16(gB1, lB1);
    gA0 += 32; gA1 += 32; gB0 += 32; gB1 += 32;
    __syncthreads();
    bf16x8 af[4], bf[4];
#pragma unroll
    for (int i = 0; i < 4; ++i) af[i] = *(bf16x8*)&As[(wr + i * 16 + lr) * 32 + g * 8];
#pragma unroll
    for (int j = 0; j < 4; ++j) bf[j] = *(bf16x8*)&Bs[(wc + j * 16 + lr) * 32 + g * 8];
#pragma unroll
    for (int i = 0; i < 4; ++i)
#pragma unroll
      for (int j = 0; j < 4; ++j)
        acc[i][j] = __builtin_amdgcn_mfma_f32_16x16x32_bf16(af[i], bf[j], acc[i][j], 0, 0, 0);
    __syncthreads();
  }

#pragma unroll
  for (int i = 0; i < 4; ++i) {
#pragma unroll
    for (int r = 0; r < 4; ++r) {
      int m = m0 + wr + i * 16 + g * 4 + r;
#pragma unroll
      for (int j = 0; j < 4; ++j) {
        int n = n0 + wc + j * 16 + lr;
        outp[(size_t)m * E_ + n] = acc[i][j][r] + bias[n];
      }
    }
  }
}

extern "C" void kernel_launch(void* const* d_in, const int* in_sizes, int n_in,
                              void* d_out, int out_size, void* d_ws, size_t ws_size,
                              hipStream_t stream) {
  const float* x      = (const float*)d_in[0];
  const float* Wqkv   = (const float*)d_in[1];
  const float* bqkv   = (const float*)d_in[2];
  const float* Wout   = (const float*)d_in[3];
  const float* bout   = (const float*)d_in[4];
  const float* Wimp   = (const float*)d_in[5];
  const float* bimp   = (const float*)d_in[6];
  const float* Walpha = (const float*)d_in[7];
  const float* balpha = (const float*)d_in[8];
  const float* thr    = (const float*)d_in[9];
  const float* log_k  = (const float*)d_in[10];
  const float* qk_sc  = (const float*)d_in[11];
  float* out = (float*)d_out;

  char* ws = (char*)d_ws;
  size_t off = 0;
  auto alloc = [&](size_t bytes) -> void* {
    void* p = (void*)(ws + off);
    off += (bytes + 255) & ~(size_t)255;
    return p;
  };
  const size_t qkv_elems = (size_t)B_ * H_ * T_ * D_;
  __bf16* xb    = (__bf16*)alloc((size_t)M_ * E_ * 2);      // dead after qkv_gemm
  __bf16* Wqkvb = (__bf16*)alloc((size_t)3 * E_ * E_ * 2);  // dead after qkv_gemm
  __bf16* Woutb = (__bf16*)alloc((size_t)E_ * E_ * 2);
  __bf16* q   = (__bf16*)alloc(qkv_elems * 2);
  __bf16* k   = (__bf16*)alloc(qkv_elems * 2);
  __bf16* v   = (__bf16*)alloc(qkv_elems * 2);
  __bf16* qh  = (__bf16*)alloc(qkv_elems * 2);
  __bf16* khn = (__bf16*)alloc(qkv_elems * 2);
  __bf16* yw  = (__bf16*)alloc((size_t)M_ * E_ * 2);
  float* alphaw = (float*)alloc((size_t)B_ * H_ * T_ * sizeof(float));
  float* spikew = (float*)alloc((size_t)M_ * sizeof(float));
  float* pml    = (float*)alloc((size_t)4096 * 32 * sizeof(float));
  // pacc (8 MB) aliases xb+Wqkvb (10 MB), both dead before attn runs
  __bf16* pacc = (__bf16*)ws;

  conv_kernel<<<1024, 256, 0, stream>>>(x, Wqkv, Wout, xb, Wqkvb, Woutb);
  imp_alpha_kernel<<<M_, 256, 0, stream>>>(x, Wimp, bimp, Walpha, balpha, thr,
                                           spikew, alphaw);
  qkv_gemm_kernel<<<dim3(24, 16), 256, 0, stream>>>(xb, Wqkvb, bqkv, q, k, v);
  hyp_kernel<<<(2 * B_ * H_ * T_) / 4, 256, 0, stream>>>(q, k, qk_sc, qh, khn);
  attn_kernel<<<1024, 256, 0, stream>>>(q, k, v, qh, khn, alphaw, log_k,
                                        pacc, pml);
  merge_kernel<<<512, 256, 0, stream>>>(pacc, pml, spikew, yw);
  out_gemm_kernel<<<dim3(8, 16), 256, 0, stream>>>(yw, Woutb, bout, out);
}